// Round 14
// baseline (78.497 us; speedup 1.0000x reference)
//
#include <hip/hip_runtime.h>
#include <cstddef>
#include <cstdint>

// KPNextBlock: M=N=50000, H=32, C=128, K=15, GROUPS=8, CPG=16 -> K*CPG=240,
// RADIUS=1.2, SIGMA=0.9.
namespace {
constexpr int H_N    = 32;
constexpr int C_F    = 128;
constexpr int K_P    = 15;
constexpr int MODC   = 240;
constexpr int ROWS_B = 64;     // active rows per MLP block
constexpr int LDS_SZ = ROWS_B * MODC * 2;   // 30720: x/h swz [0,16K) then mod
}

typedef __attribute__((ext_vector_type(8))) short short8v;
typedef __attribute__((ext_vector_type(4))) float f32x4;

__device__ __forceinline__ unsigned short bf16_hi(float f) {
    unsigned u = __builtin_bit_cast(unsigned, f);
    unsigned r = (u + 0x7FFFu + ((u >> 16) & 1u)) >> 16;
    return (unsigned short)r;
}
__device__ __forceinline__ float bf16_f(unsigned short h) {
    unsigned u = ((unsigned)h) << 16;
    return __builtin_bit_cast(float, u);
}

// ---------------------------------------------------------------------------
// Pre-pass: transpose weights to bf16 [col][k]; also zero the compaction
// counter (runs before geom_kernel in stream order).
// ---------------------------------------------------------------------------
__global__ __launch_bounds__(256)
void split_w_kernel(const float* __restrict__ w1, const float* __restrict__ w2,
                    unsigned short* __restrict__ w1t, unsigned short* __restrict__ w2t,
                    int* __restrict__ counter)
{
    const int i = blockIdx.x * 256 + threadIdx.x;
    if (i == 0) *counter = 0;
    if (i < C_F * C_F) {
        const int c = i >> 7, j = i & 127;          // w1[c][j]
        w1t[j * C_F + c] = bf16_hi(w1[i]);
    }
    const int i2 = i - C_F * C_F;
    if (i2 >= 0 && i2 < C_F * MODC) {
        const int c = i2 / MODC, j = i2 - c * MODC; // w2[c][j]
        w2t[j * C_F + c] = bf16_hi(w2[i2]);
    }
}

// ---------------------------------------------------------------------------
// Geometry + compaction: one wave per query (12.5k blocks, proven cheap in
// round 2). ~80-85% of queries have NO contributing neighbor (P(contribute)
// ~0.7%/neighbor): write out=0 and skip the MLP entirely. Active queries are
// compacted via atomicAdd (order-independent output -> deterministic).
// ---------------------------------------------------------------------------
__global__ __launch_bounds__(256)
void geom_kernel(const float* __restrict__ q_pts,
                 const float* __restrict__ s_pts,
                 const int* __restrict__ nbi,
                 const float* __restrict__ da_scale,
                 const float* __restrict__ kp,
                 int* __restrict__ counter,
                 int* __restrict__ qidx,
                 unsigned* __restrict__ pk,     // idx | nn<<20, per (active,neighbor)
                 float* __restrict__ gfl,       // infl, per (active,neighbor)
                 float* __restrict__ out,
                 int M)
{
    const int t    = threadIdx.x;
    const int lane = t & 63;
    const int r    = blockIdx.x * 4 + (t >> 6);
    if (r >= M) return;

    int   idx = 0, nn = 0;
    float fl  = 0.f;
    if (lane < H_N) {
        const float qx = q_pts[r * 3 + 0];
        const float qy = q_pts[r * 3 + 1];
        const float qz = q_pts[r * 3 + 2];
        const float das = da_scale[r];
        idx = nbi[(size_t)r * H_N + lane];
        const float sx = s_pts[idx * 3 + 0];
        const float sy = s_pts[idx * 3 + 1];
        const float sz = s_pts[idx * 3 + 2];
        // plain fp32 (no fma contraction) to match numpy rounding at argmin ties
        const float dx = __fsub_rn(sx, qx);
        const float dy = __fsub_rn(sy, qy);
        const float dz = __fsub_rn(sz, qz);
        const float dd = __fadd_rn(__fadd_rn(__fmul_rn(dx, dx), __fmul_rn(dy, dy)),
                                   __fmul_rn(dz, dz));
        // |kp| < 1.2 strictly => |d| >= 0.9 + 1.2*da implies infl == 0 exactly.
        const float reach = 0.9f + 1.2f * das;
        if (dd < reach * reach) {
            float best = 3.4e38f; int bi = 0;
            #pragma unroll
            for (int k = 0; k < K_P; ++k) {
                const float ex = __fsub_rn(dx, __fmul_rn(kp[k * 3 + 0], das));
                const float ey = __fsub_rn(dy, __fmul_rn(kp[k * 3 + 1], das));
                const float ez = __fsub_rn(dz, __fmul_rn(kp[k * 3 + 2], das));
                const float d2 = __fadd_rn(__fadd_rn(__fmul_rn(ex, ex), __fmul_rn(ey, ey)),
                                           __fmul_rn(ez, ez));
                if (d2 < best) { best = d2; bi = k; }
            }
            const float f = 1.f - sqrtf(best) / 0.9f;
            fl = fmaxf(f, 0.f);
            nn = bi;
        }
    }

    const unsigned long long mask = __ballot(fl > 0.f);
    if (mask == 0ull) {
        // inactive: output is exactly zero
        reinterpret_cast<float2*>(out + (size_t)r * C_F)[lane] = make_float2(0.f, 0.f);
        return;
    }
    int pos = 0;
    if (lane == 0) pos = atomicAdd(counter, 1);
    pos = __shfl(pos, 0);
    if (lane == 0) qidx[pos] = r;
    if (lane < H_N) {
        pk [(size_t)pos * H_N + lane] = (unsigned)idx | ((unsigned)nn << 20);
        gfl[(size_t)pos * H_N + lane] = fl;
    }
}

// ---------------------------------------------------------------------------
// Active-query fused MLP + gather (round-13 structure, active rows only):
//   gather x rows via qidx -> GEMM1 (h -> LDS) -> GEMM2 (sigmoid in regs) ->
//   mod -> LDS -> gather/accumulate from stored neighbor records.
// Grid covers worst case; blocks past count exit on a uniform load.
// ---------------------------------------------------------------------------
__global__ __launch_bounds__(512, 4)
void active_kernel(const float* __restrict__ s_feats,
                   const float* __restrict__ weights,
                   const unsigned short* __restrict__ w1t,
                   const unsigned short* __restrict__ w2t,
                   const float* __restrict__ b1,
                   const int* __restrict__ counter,
                   const int* __restrict__ qidx,
                   const unsigned* __restrict__ pk,
                   const float* __restrict__ gfl,
                   float* __restrict__ out)
{
    __shared__ __align__(16) unsigned char lds[LDS_SZ];

    const int count = *counter;
    const int r0 = blockIdx.x * ROWS_B;
    const int rows = min(count - r0, ROWS_B);
    if (rows <= 0) return;

    const int t = threadIdx.x;

    // ---- stage x (gathered rows): fp32 -> bf16, swizzled LDS [row][k] ----
    {
        const int row = t >> 3;          // 0..63
        const int k0  = (t & 7) << 4;    // 0,16,...,112
        const int src_m = (row < rows) ? qidx[r0 + row] : 0;
        const float4* src = reinterpret_cast<const float4*>(
            s_feats + (size_t)src_m * C_F + k0);
        #pragma unroll
        for (int s = 0; s < 2; ++s) {
            float v[8];
            if (row < rows) {
                const float4 a = src[s * 2 + 0];
                const float4 b = src[s * 2 + 1];
                v[0] = a.x; v[1] = a.y; v[2] = a.z; v[3] = a.w;
                v[4] = b.x; v[5] = b.y; v[6] = b.z; v[7] = b.w;
            } else {
                #pragma unroll
                for (int e = 0; e < 8; ++e) v[e] = 0.f;
            }
            short8v hv;
            #pragma unroll
            for (int e = 0; e < 8; ++e) hv[e] = (short)bf16_hi(v[e]);
            const unsigned addr = (unsigned)((row * 256 + (k0 + s * 8) * 2) ^ ((row & 7) << 4));
            *reinterpret_cast<short8v*>(lds + addr) = hv;
        }
    }
    __syncthreads();

    const int wave = t >> 6, lane = t & 63;
    const int wc = wave;           // col tile 0..7
    const int g  = lane >> 4;      // k-block
    const int ln = lane & 15;

    // ---- GEMM1: h = leaky_relu(x @ w1 + b1); wave owns col-tile wc ----
    {
        const int col = wc * 16 + ln;
        f32x4 acc[4];
        {
            const float b = b1[col];
            #pragma unroll
            for (int rt = 0; rt < 4; ++rt) acc[rt] = f32x4{b, b, b, b};
        }
        #pragma unroll
        for (int ks = 0; ks < 4; ++ks) {
            short8v a[4];
            #pragma unroll
            for (int rt = 0; rt < 4; ++rt) {
                const int row = rt * 16 + ln;
                const unsigned addr = (unsigned)((row * 256 + (ks * 32 + g * 8) * 2) ^ ((row & 7) << 4));
                a[rt] = *reinterpret_cast<const short8v*>(lds + addr);
            }
            const short8v b = *reinterpret_cast<const short8v*>(
                w1t + (size_t)col * C_F + ks * 32 + g * 8);
            #pragma unroll
            for (int rt = 0; rt < 4; ++rt)
                acc[rt] = __builtin_amdgcn_mfma_f32_16x16x32_bf16(a[rt], b, acc[rt], 0, 0, 0);
        }
        __syncthreads();   // all waves done reading x before h overwrites it

        // leaky_relu + writeback (C/D: col=ln, row=g*4+r)
        #pragma unroll
        for (int rt = 0; rt < 4; ++rt) {
            #pragma unroll
            for (int r = 0; r < 4; ++r) {
                float v = acc[rt][r];
                v = v > 0.f ? v : 0.1f * v;
                const int row = rt * 16 + g * 4 + r;
                const unsigned addr = (unsigned)((row * 256 + col * 2) ^ ((row & 7) << 4));
                *reinterpret_cast<unsigned short*>(lds + addr) = bf16_hi(v);
            }
        }
    }
    __syncthreads();

    // ---- GEMM2: mod = sigmoid(h @ w2) in registers; wave owns {wc, wc+8} ----
    f32x4 acc2[4][2];
    #pragma unroll
    for (int rt = 0; rt < 4; ++rt)
        #pragma unroll
        for (int cs = 0; cs < 2; ++cs) acc2[rt][cs] = f32x4{0.f, 0.f, 0.f, 0.f};

    #pragma unroll
    for (int ks = 0; ks < 4; ++ks) {
        short8v a[4];
        #pragma unroll
        for (int rt = 0; rt < 4; ++rt) {
            const int row = rt * 16 + ln;
            const unsigned addr = (unsigned)((row * 256 + (ks * 32 + g * 8) * 2) ^ ((row & 7) << 4));
            a[rt] = *reinterpret_cast<const short8v*>(lds + addr);
        }
        #pragma unroll
        for (int cs = 0; cs < 2; ++cs) {
            const int ctile = wc + 8 * cs;      // wave-uniform guard, static acc idx
            if (ctile < K_P) {
                const int col = ctile * 16 + ln;
                const short8v b = *reinterpret_cast<const short8v*>(
                    w2t + (size_t)col * C_F + ks * 32 + g * 8);
                #pragma unroll
                for (int rt = 0; rt < 4; ++rt)
                    acc2[rt][cs] = __builtin_amdgcn_mfma_f32_16x16x32_bf16(a[rt], b, acc2[rt][cs], 0, 0, 0);
            }
        }
    }
    #pragma unroll
    for (int rt = 0; rt < 4; ++rt)
        #pragma unroll
        for (int cs = 0; cs < 2; ++cs)
            #pragma unroll
            for (int r = 0; r < 4; ++r)
                acc2[rt][cs][r] = 1.f / (1.f + __expf(-acc2[rt][cs][r]));

    __syncthreads();   // h reads complete -> mod may overwrite the region

    // ---- mod -> LDS (linear bf16 [64][240]) ----
    #pragma unroll
    for (int rt = 0; rt < 4; ++rt) {
        #pragma unroll
        for (int cs = 0; cs < 2; ++cs) {
            const int ctile = wc + 8 * cs;
            if (ctile < K_P) {
                const int col = ctile * 16 + ln;
                #pragma unroll
                for (int r = 0; r < 4; ++r) {
                    const int row = rt * 16 + g * 4 + r;
                    *reinterpret_cast<unsigned short*>(
                        lds + row * (MODC * 2) + col * 2) = bf16_hi(acc2[rt][cs][r]);
                }
            }
        }
    }
    __syncthreads();

    // ---- gather/accumulate: 2 queries per pass (half-wave each), 4 passes ----
    const int hl   = lane & 31;      // neighbor index
    const int half = lane >> 5;
    const int c0   = hl << 2;        // 4 channels per lane
    for (int i = 0; i < 4; ++i) {
        const int ql = i * 16 + wave * 2 + half;
        const bool valid = ql < rows;
        const int pos = r0 + ql;

        int   idx = 0, nn = 0;
        float fl  = 0.f;
        if (valid) {
            const unsigned p = pk[(size_t)pos * H_N + hl];
            idx = (int)(p & 0xFFFFFu);
            nn  = (int)(p >> 20);
            fl  = gfl[(size_t)pos * H_N + hl];
        }

        const unsigned long long mask = __ballot(fl > 0.f);
        unsigned long long mymask = half ? (mask & 0xFFFFFFFF00000000ull)
                                         : (mask & 0x00000000FFFFFFFFull);
        float4 acc = {0.f, 0.f, 0.f, 0.f};
        while (mymask) {
            const int hb = __builtin_ctzll(mymask);   // absolute lane (correct half)
            mymask &= mymask - 1;
            const int   ih = __shfl(idx, hb);
            const int   nh = __shfl(nn, hb);
            const float fh = __shfl(fl, hb);
            const float4 fv = *reinterpret_cast<const float4*>(s_feats + (size_t)ih * C_F + c0);
            const float4 wv = *reinterpret_cast<const float4*>(weights + nh * C_F + c0);
            const float  mv = bf16_f(*reinterpret_cast<const unsigned short*>(
                lds + ql * (MODC * 2) + (nh * 16 + (hl >> 1)) * 2));
            const float  s  = fh * mv;
            acc.x = fmaf(fv.x * wv.x, s, acc.x);
            acc.y = fmaf(fv.y * wv.y, s, acc.y);
            acc.z = fmaf(fv.z * wv.z, s, acc.z);
            acc.w = fmaf(fv.w * wv.w, s, acc.w);
        }
        if (valid) {
            const int mq = qidx[pos];
            *reinterpret_cast<float4*>(out + (size_t)mq * C_F + c0) = acc;
        }
    }
}

// ---------------------------------------------------------------------------
extern "C" void kernel_launch(void* const* d_in, const int* in_sizes, int n_in,
                              void* d_out, int out_size, void* d_ws, size_t ws_size,
                              hipStream_t stream)
{
    const float* q_pts  = (const float*)d_in[0];
    const float* s_pts  = (const float*)d_in[1];
    const float* s_feat = (const float*)d_in[2];
    const int*   nbi    = (const int*)d_in[3];
    const float* da     = (const float*)d_in[4];
    const float* wts    = (const float*)d_in[5];
    const float* w1     = (const float*)d_in[6];
    const float* b1     = (const float*)d_in[7];
    const float* w2     = (const float*)d_in[8];
    const float* kp     = (const float*)d_in[9];
    float* out = (float*)d_out;

    const int M = in_sizes[4];   // da_scale has M elements

    // ws layout: w1t 32KB | w2t 60KB | counter | qidx[M] | pk[M*32] | gfl[M*32]
    unsigned short* w1t = (unsigned short*)d_ws;
    unsigned short* w2t = w1t + C_F * C_F;
    size_t off = ((size_t)(C_F * C_F + C_F * MODC) * sizeof(unsigned short) + 255) & ~(size_t)255;
    int* counter = (int*)((char*)d_ws + off);           off += 256;
    int* qidx    = (int*)((char*)d_ws + off);           off += (size_t)M * 4;
    off = (off + 255) & ~(size_t)255;
    unsigned* pk = (unsigned*)((char*)d_ws + off);      off += (size_t)M * H_N * 4;
    float* gfl   = (float*)((char*)d_ws + off);

    const int nsplit = (C_F * C_F + C_F * MODC + 255) / 256;
    split_w_kernel<<<dim3(nsplit), 256, 0, stream>>>(w1, w2, w1t, w2t, counter);

    geom_kernel<<<dim3((M + 3) / 4), 256, 0, stream>>>(
        q_pts, s_pts, nbi, da, kp, counter, qidx, pk, gfl, out, M);

    const int nb = (M + ROWS_B - 1) / ROWS_B;
    active_kernel<<<dim3(nb), 512, 0, stream>>>(
        s_feat, wts, w1t, w2t, b1, counter, qidx, pk, gfl, out);
}

// Round 15
// 42.629 us; speedup vs baseline: 1.8414x; 1.8414x over previous
//
#include <hip/hip_runtime.h>
#include <cstddef>
#include <cstdint>

// KPNextBlock: M=N=50000, H=32, C=128, K=15, GROUPS=8, CPG=16 -> K*CPG=240,
// RADIUS=1.2, SIGMA=0.9.
namespace {
constexpr int H_N    = 32;
constexpr int C_F    = 128;
constexpr int K_P    = 15;
constexpr int MODC   = 240;
constexpr int ROWS_B = 64;     // active rows per MLP block
constexpr int LDS_SZ = ROWS_B * MODC * 2;   // 30720: x/h swz [0,16K) then mod
constexpr int QB     = 96;     // queries per geom block (16/pass x 6 passes)
}

typedef __attribute__((ext_vector_type(8))) short short8v;
typedef __attribute__((ext_vector_type(4))) float f32x4;

__device__ __forceinline__ unsigned short bf16_hi(float f) {
    unsigned u = __builtin_bit_cast(unsigned, f);
    unsigned r = (u + 0x7FFFu + ((u >> 16) & 1u)) >> 16;
    return (unsigned short)r;
}
__device__ __forceinline__ float bf16_f(unsigned short h) {
    unsigned u = ((unsigned)h) << 16;
    return __builtin_bit_cast(float, u);
}

// ---------------------------------------------------------------------------
// Pre-pass: transpose weights to bf16 [col][k]; zero the compaction counter.
// ---------------------------------------------------------------------------
__global__ __launch_bounds__(256)
void split_w_kernel(const float* __restrict__ w1, const float* __restrict__ w2,
                    unsigned short* __restrict__ w1t, unsigned short* __restrict__ w2t,
                    int* __restrict__ counter)
{
    const int i = blockIdx.x * 256 + threadIdx.x;
    if (i == 0) *counter = 0;
    if (i < C_F * C_F) {
        const int c = i >> 7, j = i & 127;          // w1[c][j]
        w1t[j * C_F + c] = bf16_hi(w1[i]);
    }
    const int i2 = i - C_F * C_F;
    if (i2 >= 0 && i2 < C_F * MODC) {
        const int c = i2 / MODC, j = i2 - c * MODC; // w2[c][j]
        w2t[j * C_F + c] = bf16_hi(w2[i2]);
    }
}

// ---------------------------------------------------------------------------
// Geometry + BLOCK-BUFFERED compaction. 96 queries/block (2/wave x 8 waves x
// 6 passes, all 64 lanes active). Active records append to LDS via LDS-atomic
// (per-CU, cheap); ONE global atomicAdd per block (round-14's 10k same-address
// device atomics -> 521: kills the serialization that cost 55us). Inactive
// queries (~80-85%) get out=0 directly and skip the MLP entirely.
// ---------------------------------------------------------------------------
__global__ __launch_bounds__(512, 2)
void geom_kernel(const float* __restrict__ q_pts,
                 const float* __restrict__ s_pts,
                 const int* __restrict__ nbi,
                 const float* __restrict__ da_scale,
                 const float* __restrict__ kp,
                 int* __restrict__ counter,
                 int* __restrict__ qidx,
                 unsigned* __restrict__ pk,     // idx | nn<<20 per (active,neighbor)
                 float* __restrict__ gfl,       // infl per (active,neighbor)
                 float* __restrict__ out,
                 int M)
{
    __shared__ int      qidx_l[QB];
    __shared__ unsigned pk_l [QB * H_N];
    __shared__ float    gfl_l[QB * H_N];
    __shared__ int cnt_l, base_l;

    const int t    = threadIdx.x;
    const int wave = t >> 6, lane = t & 63;
    const int hl   = lane & 31;
    const int half = lane >> 5;
    const int q0   = blockIdx.x * QB;

    if (t == 0) cnt_l = 0;
    __syncthreads();

    for (int pass = 0; pass < 6; ++pass) {
        const int ql = q0 + pass * 16 + wave * 2 + half;
        const bool valid = ql < M;

        int   idx = 0, nn = 0;
        float fl  = 0.f;
        if (valid) {
            const float qx = q_pts[ql * 3 + 0];
            const float qy = q_pts[ql * 3 + 1];
            const float qz = q_pts[ql * 3 + 2];
            const float das = da_scale[ql];
            idx = nbi[(size_t)ql * H_N + hl];
            const float sx = s_pts[idx * 3 + 0];
            const float sy = s_pts[idx * 3 + 1];
            const float sz = s_pts[idx * 3 + 2];
            // plain fp32 (no fma contraction) to match numpy rounding at argmin ties
            const float dx = __fsub_rn(sx, qx);
            const float dy = __fsub_rn(sy, qy);
            const float dz = __fsub_rn(sz, qz);
            const float dd = __fadd_rn(__fadd_rn(__fmul_rn(dx, dx), __fmul_rn(dy, dy)),
                                       __fmul_rn(dz, dz));
            // |kp| < 1.2 strictly => |d| >= 0.9 + 1.2*da implies infl == 0 exactly.
            const float reach = 0.9f + 1.2f * das;
            if (dd < reach * reach) {
                float best = 3.4e38f; int bi = 0;
                #pragma unroll
                for (int k = 0; k < K_P; ++k) {
                    const float ex = __fsub_rn(dx, __fmul_rn(kp[k * 3 + 0], das));
                    const float ey = __fsub_rn(dy, __fmul_rn(kp[k * 3 + 1], das));
                    const float ez = __fsub_rn(dz, __fmul_rn(kp[k * 3 + 2], das));
                    const float d2 = __fadd_rn(__fadd_rn(__fmul_rn(ex, ex), __fmul_rn(ey, ey)),
                                               __fmul_rn(ez, ez));
                    if (d2 < best) { best = d2; bi = k; }
                }
                const float f = 1.f - sqrtf(best) / 0.9f;
                fl = fmaxf(f, 0.f);
                nn = bi;
            }
        }

        const unsigned long long mask = __ballot(fl > 0.f);
        const unsigned long long mymask = half ? (mask & 0xFFFFFFFF00000000ull)
                                               : (mask & 0x00000000FFFFFFFFull);
        if (valid && mymask == 0ull) {
            // inactive: output row is exactly zero (32 lanes x float4 = 512B)
            *reinterpret_cast<float4*>(out + (size_t)ql * C_F + hl * 4) =
                make_float4(0.f, 0.f, 0.f, 0.f);
        } else if (valid) {
            int slot = 0;
            if (hl == 0) slot = atomicAdd(&cnt_l, 1);    // LDS atomic: cheap
            slot = __shfl(slot, half * 32);
            if (hl == 0) qidx_l[slot] = ql;
            pk_l [slot * H_N + hl] = (unsigned)idx | ((unsigned)nn << 20);
            gfl_l[slot * H_N + hl] = fl;
        }
    }
    __syncthreads();

    if (t == 0) base_l = atomicAdd(counter, cnt_l);      // ONE global atomic/block
    __syncthreads();
    const int base = base_l, cnt = cnt_l;

    for (int i = t; i < cnt; i += 512) qidx[base + i] = qidx_l[i];
    for (int i = t; i < cnt * H_N; i += 512) {
        pk [(size_t)base * H_N + i] = pk_l[i];
        gfl[(size_t)base * H_N + i] = gfl_l[i];
    }
}

// ---------------------------------------------------------------------------
// MLP over ACTIVE queries only: gather x rows via qidx -> GEMM1 (h -> LDS) ->
// GEMM2 (sigmoid in regs) -> mod -> LDS -> coalesced copy-out to compacted
// global modc (bf16 [count][240], ~4.6MB at 19% active -> L2-fit).
// ---------------------------------------------------------------------------
__global__ __launch_bounds__(512, 4)
void mlp_active_kernel(const float* __restrict__ s_feats,
                       const unsigned short* __restrict__ w1t,
                       const unsigned short* __restrict__ w2t,
                       const float* __restrict__ b1,
                       const int* __restrict__ counter,
                       const int* __restrict__ qidx,
                       unsigned short* __restrict__ modc)
{
    __shared__ __align__(16) unsigned char lds[LDS_SZ];

    const int count = *counter;
    const int r0 = blockIdx.x * ROWS_B;
    const int rows = min(count - r0, ROWS_B);
    if (rows <= 0) return;

    const int t = threadIdx.x;

    // ---- stage x (gathered rows): fp32 -> bf16, swizzled LDS [row][k] ----
    {
        const int row = t >> 3;          // 0..63
        const int k0  = (t & 7) << 4;    // 0,16,...,112
        const int src_m = (row < rows) ? qidx[r0 + row] : 0;
        const float4* src = reinterpret_cast<const float4*>(
            s_feats + (size_t)src_m * C_F + k0);
        #pragma unroll
        for (int s = 0; s < 2; ++s) {
            float v[8];
            if (row < rows) {
                const float4 a = src[s * 2 + 0];
                const float4 b = src[s * 2 + 1];
                v[0] = a.x; v[1] = a.y; v[2] = a.z; v[3] = a.w;
                v[4] = b.x; v[5] = b.y; v[6] = b.z; v[7] = b.w;
            } else {
                #pragma unroll
                for (int e = 0; e < 8; ++e) v[e] = 0.f;
            }
            short8v hv;
            #pragma unroll
            for (int e = 0; e < 8; ++e) hv[e] = (short)bf16_hi(v[e]);
            const unsigned addr = (unsigned)((row * 256 + (k0 + s * 8) * 2) ^ ((row & 7) << 4));
            *reinterpret_cast<short8v*>(lds + addr) = hv;
        }
    }
    __syncthreads();

    const int wave = t >> 6, lane = t & 63;
    const int wc = wave;           // col tile 0..7
    const int g  = lane >> 4;      // k-block
    const int ln = lane & 15;

    // ---- GEMM1: h = leaky_relu(x @ w1 + b1); wave owns col-tile wc ----
    {
        const int col = wc * 16 + ln;
        f32x4 acc[4];
        {
            const float b = b1[col];
            #pragma unroll
            for (int rt = 0; rt < 4; ++rt) acc[rt] = f32x4{b, b, b, b};
        }
        #pragma unroll
        for (int ks = 0; ks < 4; ++ks) {
            short8v a[4];
            #pragma unroll
            for (int rt = 0; rt < 4; ++rt) {
                const int row = rt * 16 + ln;
                const unsigned addr = (unsigned)((row * 256 + (ks * 32 + g * 8) * 2) ^ ((row & 7) << 4));
                a[rt] = *reinterpret_cast<const short8v*>(lds + addr);
            }
            const short8v b = *reinterpret_cast<const short8v*>(
                w1t + (size_t)col * C_F + ks * 32 + g * 8);
            #pragma unroll
            for (int rt = 0; rt < 4; ++rt)
                acc[rt] = __builtin_amdgcn_mfma_f32_16x16x32_bf16(a[rt], b, acc[rt], 0, 0, 0);
        }
        __syncthreads();   // all waves done reading x before h overwrites it

        // leaky_relu + writeback (C/D: col=ln, row=g*4+r)
        #pragma unroll
        for (int rt = 0; rt < 4; ++rt) {
            #pragma unroll
            for (int r = 0; r < 4; ++r) {
                float v = acc[rt][r];
                v = v > 0.f ? v : 0.1f * v;
                const int row = rt * 16 + g * 4 + r;
                const unsigned addr = (unsigned)((row * 256 + col * 2) ^ ((row & 7) << 4));
                *reinterpret_cast<unsigned short*>(lds + addr) = bf16_hi(v);
            }
        }
    }
    __syncthreads();

    // ---- GEMM2: mod = sigmoid(h @ w2) in registers; wave owns {wc, wc+8} ----
    f32x4 acc2[4][2];
    #pragma unroll
    for (int rt = 0; rt < 4; ++rt)
        #pragma unroll
        for (int cs = 0; cs < 2; ++cs) acc2[rt][cs] = f32x4{0.f, 0.f, 0.f, 0.f};

    #pragma unroll
    for (int ks = 0; ks < 4; ++ks) {
        short8v a[4];
        #pragma unroll
        for (int rt = 0; rt < 4; ++rt) {
            const int row = rt * 16 + ln;
            const unsigned addr = (unsigned)((row * 256 + (ks * 32 + g * 8) * 2) ^ ((row & 7) << 4));
            a[rt] = *reinterpret_cast<const short8v*>(lds + addr);
        }
        #pragma unroll
        for (int cs = 0; cs < 2; ++cs) {
            const int ctile = wc + 8 * cs;      // wave-uniform guard, static acc idx
            if (ctile < K_P) {
                const int col = ctile * 16 + ln;
                const short8v b = *reinterpret_cast<const short8v*>(
                    w2t + (size_t)col * C_F + ks * 32 + g * 8);
                #pragma unroll
                for (int rt = 0; rt < 4; ++rt)
                    acc2[rt][cs] = __builtin_amdgcn_mfma_f32_16x16x32_bf16(a[rt], b, acc2[rt][cs], 0, 0, 0);
            }
        }
    }
    #pragma unroll
    for (int rt = 0; rt < 4; ++rt)
        #pragma unroll
        for (int cs = 0; cs < 2; ++cs)
            #pragma unroll
            for (int r = 0; r < 4; ++r)
                acc2[rt][cs][r] = 1.f / (1.f + __expf(-acc2[rt][cs][r]));

    __syncthreads();   // h reads complete -> mod may overwrite the region

    // ---- mod -> LDS (linear bf16 [64][240]) ----
    #pragma unroll
    for (int rt = 0; rt < 4; ++rt) {
        #pragma unroll
        for (int cs = 0; cs < 2; ++cs) {
            const int ctile = wc + 8 * cs;
            if (ctile < K_P) {
                const int col = ctile * 16 + ln;
                #pragma unroll
                for (int r = 0; r < 4; ++r) {
                    const int row = rt * 16 + g * 4 + r;
                    *reinterpret_cast<unsigned short*>(
                        lds + row * (MODC * 2) + col * 2) = bf16_hi(acc2[rt][cs][r]);
                }
            }
        }
    }
    __syncthreads();

    // ---- coalesced copy-out: rows*30 x 16B ----
    for (int gi = t; gi < rows * 30; gi += 512) {
        const int row = gi / 30, u = gi - row * 30;
        const short8v v = *reinterpret_cast<const short8v*>(lds + row * (MODC * 2) + u * 16);
        *reinterpret_cast<short8v*>(modc + (size_t)(r0 + row) * MODC + u * 8) = v;
    }
}

// ---------------------------------------------------------------------------
// Gather over active queries: 1 query per half-wave (8/block, ~1200 effective
// blocks) -> massive TLP hides the random s_feats/weights loads.
// ---------------------------------------------------------------------------
__global__ __launch_bounds__(256)
void gather_kernel(const float* __restrict__ s_feats,
                   const float* __restrict__ weights,
                   const int* __restrict__ counter,
                   const int* __restrict__ qidx,
                   const unsigned* __restrict__ pk,
                   const float* __restrict__ gfl,
                   const unsigned short* __restrict__ modc,
                   float* __restrict__ out)
{
    const int count = *counter;
    if (blockIdx.x * 8 >= count) return;     // wave-uniform early exit

    const int t    = threadIdx.x;
    const int lane = t & 63;
    const int hl   = lane & 31;
    const int half = lane >> 5;
    const int p    = blockIdx.x * 8 + (t >> 5);   // position in compacted list
    const bool valid = p < count;

    int   idx = 0, nn = 0;
    float fl  = 0.f;
    if (valid) {
        const unsigned r = pk[(size_t)p * H_N + hl];
        idx = (int)(r & 0xFFFFFu);
        nn  = (int)(r >> 20);
        fl  = gfl[(size_t)p * H_N + hl];
    }

    const unsigned long long mask = __ballot(fl > 0.f);
    unsigned long long mymask = half ? (mask & 0xFFFFFFFF00000000ull)
                                     : (mask & 0x00000000FFFFFFFFull);
    const int c0 = hl << 2;                  // 4 channels per lane
    float4 acc = {0.f, 0.f, 0.f, 0.f};
    while (mymask) {
        const int hb = __builtin_ctzll(mymask);   // absolute lane (correct half)
        mymask &= mymask - 1;
        const int   ih = __shfl(idx, hb);
        const int   nh = __shfl(nn, hb);
        const float fh = __shfl(fl, hb);
        const float4 fv = *reinterpret_cast<const float4*>(s_feats + (size_t)ih * C_F + c0);
        const float4 wv = *reinterpret_cast<const float4*>(weights + nh * C_F + c0);
        const float  mv = bf16_f(modc[(size_t)p * MODC + nh * 16 + (hl >> 1)]);
        const float  s  = fh * mv;
        acc.x = fmaf(fv.x * wv.x, s, acc.x);
        acc.y = fmaf(fv.y * wv.y, s, acc.y);
        acc.z = fmaf(fv.z * wv.z, s, acc.z);
        acc.w = fmaf(fv.w * wv.w, s, acc.w);
    }
    if (valid) {
        const int mq = qidx[p];
        *reinterpret_cast<float4*>(out + (size_t)mq * C_F + c0) = acc;
    }
}

// ---------------------------------------------------------------------------
extern "C" void kernel_launch(void* const* d_in, const int* in_sizes, int n_in,
                              void* d_out, int out_size, void* d_ws, size_t ws_size,
                              hipStream_t stream)
{
    const float* q_pts  = (const float*)d_in[0];
    const float* s_pts  = (const float*)d_in[1];
    const float* s_feat = (const float*)d_in[2];
    const int*   nbi    = (const int*)d_in[3];
    const float* da     = (const float*)d_in[4];
    const float* wts    = (const float*)d_in[5];
    const float* w1     = (const float*)d_in[6];
    const float* b1     = (const float*)d_in[7];
    const float* w2     = (const float*)d_in[8];
    const float* kp     = (const float*)d_in[9];
    float* out = (float*)d_out;

    const int M = in_sizes[4];   // da_scale has M elements

    // ws: w1t 32KB | w2t 60KB | counter | qidx[M] | pk[M*32] | gfl[M*32] | modc[M*240]
    unsigned short* w1t = (unsigned short*)d_ws;
    unsigned short* w2t = w1t + C_F * C_F;
    size_t off = ((size_t)(C_F * C_F + C_F * MODC) * sizeof(unsigned short) + 255) & ~(size_t)255;
    int* counter = (int*)((char*)d_ws + off);           off += 256;
    int* qidx    = (int*)((char*)d_ws + off);           off += (size_t)M * 4;
    off = (off + 255) & ~(size_t)255;
    unsigned* pk = (unsigned*)((char*)d_ws + off);      off += (size_t)M * H_N * 4;
    float* gfl   = (float*)((char*)d_ws + off);         off += (size_t)M * H_N * 4;
    unsigned short* modc = (unsigned short*)((char*)d_ws + off);

    const int nsplit = (C_F * C_F + C_F * MODC + 255) / 256;
    split_w_kernel<<<dim3(nsplit), 256, 0, stream>>>(w1, w2, w1t, w2t, counter);

    geom_kernel<<<dim3((M + QB - 1) / QB), 512, 0, stream>>>(
        q_pts, s_pts, nbi, da, kp, counter, qidx, pk, gfl, out, M);

    mlp_active_kernel<<<dim3((M + ROWS_B - 1) / ROWS_B), 512, 0, stream>>>(
        s_feat, w1t, w2t, b1, counter, qidx, modc);

    gather_kernel<<<dim3((M + 7) / 8), 256, 0, stream>>>(
        s_feat, wts, counter, qidx, pk, gfl, modc, out);
}

// Round 16
// 41.760 us; speedup vs baseline: 1.8797x; 1.0208x over previous
//
#include <hip/hip_runtime.h>
#include <cstddef>
#include <cstdint>

// KPNextBlock: M=N=50000, H=32, C=128, K=15, GROUPS=8, CPG=16 -> K*CPG=240,
// RADIUS=1.2, SIGMA=0.9.
namespace {
constexpr int H_N    = 32;
constexpr int C_F    = 128;
constexpr int K_P    = 15;
constexpr int MODC   = 240;
constexpr int ROWS_B = 64;     // active rows per MLP block
constexpr int LDS_SZ = ROWS_B * MODC * 2;   // 30720: x/h swz [0,16K) then mod
constexpr int QB     = 96;     // queries per geom block (16/pass x 6 passes)
}

typedef __attribute__((ext_vector_type(8))) short short8v;
typedef __attribute__((ext_vector_type(4))) float f32x4;

__device__ __forceinline__ unsigned short bf16_hi(float f) {
    unsigned u = __builtin_bit_cast(unsigned, f);
    unsigned r = (u + 0x7FFFu + ((u >> 16) & 1u)) >> 16;
    return (unsigned short)r;
}
__device__ __forceinline__ float bf16_f(unsigned short h) {
    unsigned u = ((unsigned)h) << 16;
    return __builtin_bit_cast(float, u);
}

// ---------------------------------------------------------------------------
// Pre-pass: transpose weights to bf16 [col][k]; zero the compaction counter.
// ---------------------------------------------------------------------------
__global__ __launch_bounds__(256)
void split_w_kernel(const float* __restrict__ w1, const float* __restrict__ w2,
                    unsigned short* __restrict__ w1t, unsigned short* __restrict__ w2t,
                    int* __restrict__ counter)
{
    const int i = blockIdx.x * 256 + threadIdx.x;
    if (i == 0) *counter = 0;
    if (i < C_F * C_F) {
        const int c = i >> 7, j = i & 127;          // w1[c][j]
        w1t[j * C_F + c] = bf16_hi(w1[i]);
    }
    const int i2 = i - C_F * C_F;
    if (i2 >= 0 && i2 < C_F * MODC) {
        const int c = i2 / MODC, j = i2 - c * MODC; // w2[c][j]
        w2t[j * C_F + c] = bf16_hi(w2[i2]);
    }
}

// ---------------------------------------------------------------------------
// Geometry + block-buffered compaction, SOFTWARE-PIPELINED:
//   phase A: all 6 passes' q/nbi loads (independent);
//   phase B: all 6 passes' s_pts loads (one dep level);
//   phase C: compute + ballot + LDS append / zero-write.
// Round-15 ran the 6 dependent chains serially (~6.6k cyc/thread floor).
// One global atomicAdd per block.
// ---------------------------------------------------------------------------
__global__ __launch_bounds__(512, 2)
void geom_kernel(const float* __restrict__ q_pts,
                 const float* __restrict__ s_pts,
                 const int* __restrict__ nbi,
                 const float* __restrict__ da_scale,
                 const float* __restrict__ kp,
                 int* __restrict__ counter,
                 int* __restrict__ qidx,
                 unsigned* __restrict__ pk,     // idx | nn<<20 per (active,neighbor)
                 float* __restrict__ gfl,       // infl per (active,neighbor)
                 float* __restrict__ out,
                 int M)
{
    __shared__ int      qidx_l[QB];
    __shared__ unsigned pk_l [QB * H_N];
    __shared__ float    gfl_l[QB * H_N];
    __shared__ int cnt_l, base_l;

    const int t    = threadIdx.x;
    const int wave = t >> 6, lane = t & 63;
    const int hl   = lane & 31;
    const int half = lane >> 5;
    const int q0   = blockIdx.x * QB;

    if (t == 0) cnt_l = 0;
    __syncthreads();

    // ---- phase A: independent loads for all 6 passes ----
    float qx[6], qy[6], qz[6], das[6];
    int   idx[6];
    bool  valid[6];
    #pragma unroll
    for (int p = 0; p < 6; ++p) {
        const int ql = q0 + p * 16 + wave * 2 + half;
        valid[p] = ql < M;
        const int qc = valid[p] ? ql : 0;
        qx[p]  = q_pts[qc * 3 + 0];
        qy[p]  = q_pts[qc * 3 + 1];
        qz[p]  = q_pts[qc * 3 + 2];
        das[p] = da_scale[qc];
        idx[p] = nbi[(size_t)qc * H_N + hl];
    }
    // ---- phase B: dependent s_pts loads (all 6 in flight) ----
    float sx[6], sy[6], sz[6];
    #pragma unroll
    for (int p = 0; p < 6; ++p) {
        sx[p] = s_pts[idx[p] * 3 + 0];
        sy[p] = s_pts[idx[p] * 3 + 1];
        sz[p] = s_pts[idx[p] * 3 + 2];
    }

    // ---- phase C: compute + append / zero-write ----
    #pragma unroll
    for (int p = 0; p < 6; ++p) {
        const int ql = q0 + p * 16 + wave * 2 + half;
        int   nn = 0;
        float fl = 0.f;
        if (valid[p]) {
            // plain fp32 (no fma contraction) to match numpy rounding at argmin ties
            const float dx = __fsub_rn(sx[p], qx[p]);
            const float dy = __fsub_rn(sy[p], qy[p]);
            const float dz = __fsub_rn(sz[p], qz[p]);
            const float dd = __fadd_rn(__fadd_rn(__fmul_rn(dx, dx), __fmul_rn(dy, dy)),
                                       __fmul_rn(dz, dz));
            // |kp| < 1.2 strictly => |d| >= 0.9 + 1.2*da implies infl == 0 exactly.
            const float reach = 0.9f + 1.2f * das[p];
            if (dd < reach * reach) {
                float best = 3.4e38f; int bi = 0;
                #pragma unroll
                for (int k = 0; k < K_P; ++k) {
                    const float ex = __fsub_rn(dx, __fmul_rn(kp[k * 3 + 0], das[p]));
                    const float ey = __fsub_rn(dy, __fmul_rn(kp[k * 3 + 1], das[p]));
                    const float ez = __fsub_rn(dz, __fmul_rn(kp[k * 3 + 2], das[p]));
                    const float d2 = __fadd_rn(__fadd_rn(__fmul_rn(ex, ex), __fmul_rn(ey, ey)),
                                               __fmul_rn(ez, ez));
                    if (d2 < best) { best = d2; bi = k; }
                }
                const float f = 1.f - sqrtf(best) / 0.9f;
                fl = fmaxf(f, 0.f);
                nn = bi;
            }
        }

        const unsigned long long mask = __ballot(fl > 0.f);
        const unsigned long long mymask = half ? (mask & 0xFFFFFFFF00000000ull)
                                               : (mask & 0x00000000FFFFFFFFull);
        if (valid[p] && mymask == 0ull) {
            // inactive: output row is exactly zero (32 lanes x float4 = 512B)
            *reinterpret_cast<float4*>(out + (size_t)ql * C_F + hl * 4) =
                make_float4(0.f, 0.f, 0.f, 0.f);
        } else if (valid[p]) {
            int slot = 0;
            if (hl == 0) slot = atomicAdd(&cnt_l, 1);    // LDS atomic: cheap
            slot = __shfl(slot, half * 32);
            if (hl == 0) qidx_l[slot] = ql;
            pk_l [slot * H_N + hl] = (unsigned)idx[p] | ((unsigned)nn << 20);
            gfl_l[slot * H_N + hl] = fl;
        }
    }
    __syncthreads();

    if (t == 0) base_l = atomicAdd(counter, cnt_l);      // ONE global atomic/block
    __syncthreads();
    const int base = base_l, cnt = cnt_l;

    for (int i = t; i < cnt; i += 512) qidx[base + i] = qidx_l[i];
    for (int i = t; i < cnt * H_N; i += 512) {
        pk [(size_t)base * H_N + i] = pk_l[i];
        gfl[(size_t)base * H_N + i] = gfl_l[i];
    }
}

// ---------------------------------------------------------------------------
// Active-query fused MLP + gather. ~150 live blocks -> wall = per-block
// latency, so ALL weight fragments (12 x 16B/lane) and gather records are
// prefetched into registers at entry, overlapping the x-stage. VGPR ~107
// under the (512,2)=128 cap -> spill-free.
//   stage x -> GEMM1 (prefetched w1) -> h -> GEMM2 (prefetched w2) ->
//   sigmoid -> mod -> LDS -> gather tail (records, mod from LDS) -> out.
// ---------------------------------------------------------------------------
__global__ __launch_bounds__(512, 2)
void active_kernel(const float* __restrict__ s_feats,
                   const float* __restrict__ weights,
                   const unsigned short* __restrict__ w1t,
                   const unsigned short* __restrict__ w2t,
                   const float* __restrict__ b1,
                   const int* __restrict__ counter,
                   const int* __restrict__ qidx,
                   const unsigned* __restrict__ pk,
                   const float* __restrict__ gfl,
                   float* __restrict__ out)
{
    __shared__ __align__(16) unsigned char lds[LDS_SZ];

    const int count = *counter;
    const int r0 = blockIdx.x * ROWS_B;
    const int rows = min(count - r0, ROWS_B);
    if (rows <= 0) return;

    const int t = threadIdx.x;
    const int wave = t >> 6, lane = t & 63;
    const int wc = wave;           // col tile 0..7
    const int g  = lane >> 4;      // k-block
    const int ln = lane & 15;
    const int hl   = lane & 31;
    const int half = lane >> 5;

    // ---- prefetch weight fragments into registers (independent) ----
    short8v w1f[4];
    #pragma unroll
    for (int ks = 0; ks < 4; ++ks)
        w1f[ks] = *reinterpret_cast<const short8v*>(
            w1t + (size_t)(wc * 16 + ln) * C_F + ks * 32 + g * 8);
    short8v w2f[4][2];
    #pragma unroll
    for (int ks = 0; ks < 4; ++ks) {
        #pragma unroll
        for (int cs = 0; cs < 2; ++cs) {
            const int ctile = wc + 8 * cs;
            const int colc = (ctile < K_P ? ctile : 0) * 16 + ln;   // clamp for safe load
            w2f[ks][cs] = *reinterpret_cast<const short8v*>(
                w2t + (size_t)colc * C_F + ks * 32 + g * 8);
        }
    }

    // ---- prefetch gather records (independent) ----
    unsigned pkr[4];
    float    flr[4];
    int      qir[4];
    #pragma unroll
    for (int i = 0; i < 4; ++i) {
        const int ql = i * 16 + wave * 2 + half;
        const bool v = ql < rows;
        const int pos = r0 + (v ? ql : 0);
        pkr[i] = pk[(size_t)pos * H_N + hl];
        flr[i] = v ? gfl[(size_t)pos * H_N + hl] : 0.f;
        qir[i] = qidx[pos];
    }

    // ---- stage x (gathered rows): fp32 -> bf16, swizzled LDS [row][k] ----
    {
        const int row = t >> 3;          // 0..63
        const int k0  = (t & 7) << 4;    // 0,16,...,112
        const int src_m = (row < rows) ? qidx[r0 + row] : 0;
        const float4* src = reinterpret_cast<const float4*>(
            s_feats + (size_t)src_m * C_F + k0);
        #pragma unroll
        for (int s = 0; s < 2; ++s) {
            float v[8];
            if (row < rows) {
                const float4 a = src[s * 2 + 0];
                const float4 b = src[s * 2 + 1];
                v[0] = a.x; v[1] = a.y; v[2] = a.z; v[3] = a.w;
                v[4] = b.x; v[5] = b.y; v[6] = b.z; v[7] = b.w;
            } else {
                #pragma unroll
                for (int e = 0; e < 8; ++e) v[e] = 0.f;
            }
            short8v hv;
            #pragma unroll
            for (int e = 0; e < 8; ++e) hv[e] = (short)bf16_hi(v[e]);
            const unsigned addr = (unsigned)((row * 256 + (k0 + s * 8) * 2) ^ ((row & 7) << 4));
            *reinterpret_cast<short8v*>(lds + addr) = hv;
        }
    }
    __syncthreads();

    // ---- GEMM1: h = leaky_relu(x @ w1 + b1); wave owns col-tile wc ----
    {
        const int col = wc * 16 + ln;
        f32x4 acc[4];
        {
            const float b = b1[col];
            #pragma unroll
            for (int rt = 0; rt < 4; ++rt) acc[rt] = f32x4{b, b, b, b};
        }
        #pragma unroll
        for (int ks = 0; ks < 4; ++ks) {
            short8v a[4];
            #pragma unroll
            for (int rt = 0; rt < 4; ++rt) {
                const int row = rt * 16 + ln;
                const unsigned addr = (unsigned)((row * 256 + (ks * 32 + g * 8) * 2) ^ ((row & 7) << 4));
                a[rt] = *reinterpret_cast<const short8v*>(lds + addr);
            }
            #pragma unroll
            for (int rt = 0; rt < 4; ++rt)
                acc[rt] = __builtin_amdgcn_mfma_f32_16x16x32_bf16(a[rt], w1f[ks], acc[rt], 0, 0, 0);
        }
        __syncthreads();   // all waves done reading x before h overwrites it

        // leaky_relu + writeback (C/D: col=ln, row=g*4+r)
        #pragma unroll
        for (int rt = 0; rt < 4; ++rt) {
            #pragma unroll
            for (int r = 0; r < 4; ++r) {
                float v = acc[rt][r];
                v = v > 0.f ? v : 0.1f * v;
                const int row = rt * 16 + g * 4 + r;
                const unsigned addr = (unsigned)((row * 256 + col * 2) ^ ((row & 7) << 4));
                *reinterpret_cast<unsigned short*>(lds + addr) = bf16_hi(v);
            }
        }
    }
    __syncthreads();

    // ---- GEMM2: mod = sigmoid(h @ w2) in registers; wave owns {wc, wc+8} ----
    f32x4 acc2[4][2];
    #pragma unroll
    for (int rt = 0; rt < 4; ++rt)
        #pragma unroll
        for (int cs = 0; cs < 2; ++cs) acc2[rt][cs] = f32x4{0.f, 0.f, 0.f, 0.f};

    #pragma unroll
    for (int ks = 0; ks < 4; ++ks) {
        short8v a[4];
        #pragma unroll
        for (int rt = 0; rt < 4; ++rt) {
            const int row = rt * 16 + ln;
            const unsigned addr = (unsigned)((row * 256 + (ks * 32 + g * 8) * 2) ^ ((row & 7) << 4));
            a[rt] = *reinterpret_cast<const short8v*>(lds + addr);
        }
        #pragma unroll
        for (int cs = 0; cs < 2; ++cs) {
            const int ctile = wc + 8 * cs;      // wave-uniform guard, static acc idx
            if (ctile < K_P) {
                #pragma unroll
                for (int rt = 0; rt < 4; ++rt)
                    acc2[rt][cs] = __builtin_amdgcn_mfma_f32_16x16x32_bf16(a[rt], w2f[ks][cs], acc2[rt][cs], 0, 0, 0);
            }
        }
    }
    #pragma unroll
    for (int rt = 0; rt < 4; ++rt)
        #pragma unroll
        for (int cs = 0; cs < 2; ++cs)
            #pragma unroll
            for (int r = 0; r < 4; ++r)
                acc2[rt][cs][r] = 1.f / (1.f + __expf(-acc2[rt][cs][r]));

    __syncthreads();   // h reads complete -> mod may overwrite the region

    // ---- mod -> LDS (linear bf16 [64][240]) ----
    #pragma unroll
    for (int rt = 0; rt < 4; ++rt) {
        #pragma unroll
        for (int cs = 0; cs < 2; ++cs) {
            const int ctile = wc + 8 * cs;
            if (ctile < K_P) {
                const int col = ctile * 16 + ln;
                #pragma unroll
                for (int r = 0; r < 4; ++r) {
                    const int row = rt * 16 + g * 4 + r;
                    *reinterpret_cast<unsigned short*>(
                        lds + row * (MODC * 2) + col * 2) = bf16_hi(acc2[rt][cs][r]);
                }
            }
        }
    }
    __syncthreads();

    // ---- gather tail: 2 queries per pass (half-wave each), 4 passes ----
    const int c0 = hl << 2;          // 4 channels per lane
    #pragma unroll
    for (int i = 0; i < 4; ++i) {
        const int ql = i * 16 + wave * 2 + half;
        const bool valid = ql < rows;

        const int   idx = (int)(pkr[i] & 0xFFFFFu);
        const int   nn  = (int)(pkr[i] >> 20);
        const float fl  = flr[i];

        const unsigned long long mask = __ballot(fl > 0.f);
        unsigned long long mymask = half ? (mask & 0xFFFFFFFF00000000ull)
                                         : (mask & 0x00000000FFFFFFFFull);
        float4 acc = {0.f, 0.f, 0.f, 0.f};
        while (mymask) {
            const int hb = __builtin_ctzll(mymask);   // absolute lane (correct half)
            mymask &= mymask - 1;
            const int   ih = __shfl(idx, hb);
            const int   nh = __shfl(nn, hb);
            const float fh = __shfl(fl, hb);
            const float4 fv = *reinterpret_cast<const float4*>(s_feats + (size_t)ih * C_F + c0);
            const float4 wv = *reinterpret_cast<const float4*>(weights + nh * C_F + c0);
            const float  mv = bf16_f(*reinterpret_cast<const unsigned short*>(
                lds + ql * (MODC * 2) + (nh * 16 + (hl >> 1)) * 2));
            const float  s  = fh * mv;
            acc.x = fmaf(fv.x * wv.x, s, acc.x);
            acc.y = fmaf(fv.y * wv.y, s, acc.y);
            acc.z = fmaf(fv.z * wv.z, s, acc.z);
            acc.w = fmaf(fv.w * wv.w, s, acc.w);
        }
        if (valid)
            *reinterpret_cast<float4*>(out + (size_t)qir[i] * C_F + c0) = acc;
    }
}

// ---------------------------------------------------------------------------
extern "C" void kernel_launch(void* const* d_in, const int* in_sizes, int n_in,
                              void* d_out, int out_size, void* d_ws, size_t ws_size,
                              hipStream_t stream)
{
    const float* q_pts  = (const float*)d_in[0];
    const float* s_pts  = (const float*)d_in[1];
    const float* s_feat = (const float*)d_in[2];
    const int*   nbi    = (const int*)d_in[3];
    const float* da     = (const float*)d_in[4];
    const float* wts    = (const float*)d_in[5];
    const float* w1     = (const float*)d_in[6];
    const float* b1     = (const float*)d_in[7];
    const float* w2     = (const float*)d_in[8];
    const float* kp     = (const float*)d_in[9];
    float* out = (float*)d_out;

    const int M = in_sizes[4];   // da_scale has M elements

    // ws: w1t 32KB | w2t 60KB | counter | qidx[M] | pk[M*32] | gfl[M*32]
    unsigned short* w1t = (unsigned short*)d_ws;
    unsigned short* w2t = w1t + C_F * C_F;
    size_t off = ((size_t)(C_F * C_F + C_F * MODC) * sizeof(unsigned short) + 255) & ~(size_t)255;
    int* counter = (int*)((char*)d_ws + off);           off += 256;
    int* qidx    = (int*)((char*)d_ws + off);           off += (size_t)M * 4;
    off = (off + 255) & ~(size_t)255;
    unsigned* pk = (unsigned*)((char*)d_ws + off);      off += (size_t)M * H_N * 4;
    float* gfl   = (float*)((char*)d_ws + off);

    const int nsplit = (C_F * C_F + C_F * MODC + 255) / 256;
    split_w_kernel<<<dim3(nsplit), 256, 0, stream>>>(w1, w2, w1t, w2t, counter);

    geom_kernel<<<dim3((M + QB - 1) / QB), 512, 0, stream>>>(
        q_pts, s_pts, nbi, da, kp, counter, qidx, pk, gfl, out, M);

    active_kernel<<<dim3((M + ROWS_B - 1) / ROWS_B), 512, 0, stream>>>(
        s_feat, wts, w1t, w2t, b1, counter, qidx, pk, gfl, out);
}